// Round 1
// baseline (288.970 us; speedup 1.0000x reference)
//
#include <hip/hip_runtime.h>

typedef unsigned short u16;
typedef __attribute__((ext_vector_type(8))) short bf16x8;
typedef __attribute__((ext_vector_type(4))) float f32x4;
typedef __attribute__((ext_vector_type(4))) unsigned short u16x4;

#define B_  2
#define S_  2048
#define H_  1024
#define NH_ 16
#define HD_ 64
#define MR_ (B_*S_)   /* 4096 rows */
#define K_  H_

__device__ __forceinline__ u16 f2bf(float f) {
  union { float f; unsigned u; } x; x.f = f;
  unsigned r = x.u + 0x7fffu + ((x.u >> 16) & 1u);
  return (u16)(r >> 16);
}

__device__ __forceinline__ void gload16(const u16* g, u16* l) {
  __builtin_amdgcn_global_load_lds((const __attribute__((address_space(1))) void*)g,
                                   (__attribute__((address_space(3))) void*)l, 16, 0, 0);
}

// ---------------- convert q,k,v f32 -> bf16 ----------------
__global__ __launch_bounds__(256) void cvt3(const float* __restrict__ q, const float* __restrict__ k,
                                            const float* __restrict__ v, u16* __restrict__ dst) {
  const float* src = blockIdx.z == 0 ? q : blockIdx.z == 1 ? k : v;
  u16* d = dst + (size_t)blockIdx.z * MR_ * H_;
  size_t i = ((size_t)blockIdx.x * 256 + threadIdx.x) * 4;
  float4 f = *(const float4*)(src + i);
  u16x4 o = { f2bf(f.x), f2bf(f.y), f2bf(f.z), f2bf(f.w) };
  *(u16x4*)(d + i) = o;
}

// ---------------- transpose + convert weights: Wt[n][k] = bf16(W[k][n]) ----------------
__global__ __launch_bounds__(256) void wtrans(const float* __restrict__ Wq, const float* __restrict__ Wk,
                                              const float* __restrict__ Wv, const float* __restrict__ Wo,
                                              u16* __restrict__ wt) {
  const int z = blockIdx.z;
  const float* W = z == 0 ? Wq : z == 1 ? Wk : z == 2 ? Wv : Wo;
  u16* Wt = wt + (size_t)z * H_ * K_;
  __shared__ float t[32][33];
  const int n0 = blockIdx.x * 32, k0 = blockIdx.y * 32;
  const int tx = threadIdx.x & 31, ty = threadIdx.x >> 5;  // ty 0..7
  #pragma unroll
  for (int i = 0; i < 4; i++) t[ty + 8*i][tx] = W[(size_t)(k0 + ty + 8*i) * H_ + n0 + tx];
  __syncthreads();
  #pragma unroll
  for (int i = 0; i < 4; i++) Wt[(size_t)(n0 + ty + 8*i) * K_ + k0 + tx] = f2bf(t[tx][ty + 8*i]);
}

// ---------------- GEMM body: A[M,K] bf16 row-major, Bt[N,K] bf16 row-major ----------------
// 128x128 tile, BK=64, 256 threads (4 waves, 2x2), mfma_f32_16x16x32_bf16.
// LDS linear [row][64] bf16 (128B rows, 8x16B slots); both-sides XOR swizzle: slot ^= row&7.
template <int BF16OUT>
__device__ __forceinline__ void gemm_body(const u16* __restrict__ A, const u16* __restrict__ Bt,
                                          const float* __restrict__ bias, u16* __restrict__ Obf,
                                          float* __restrict__ Of, int m_tile, int n_tile) {
  __shared__ u16 ldsA[128 * 64];
  __shared__ u16 ldsB[128 * 64];
  const int tid = threadIdx.x;
  const int lane = tid & 63, wave = tid >> 6;
  const int wm = wave >> 1, wn = wave & 1;
  const int m0 = m_tile * 128, n0 = n_tile * 128;

  f32x4 acc[4][4] = {};

  // staging: thread t, issue j -> LDS row j*32 + t/8, slot t%8 (linear dest).
  // source pre-swizzled so LDS[row][slot] holds logical slot (slot ^ (row&7)).
  const int srow = tid >> 3;                     // 0..31
  const int sslot = (tid & 7) ^ (srow & 7);      // logical k-slot to fetch
  const u16* ga = A + (size_t)(m0 + srow) * K_ + sslot * 8;
  const u16* gb = Bt + (size_t)(n0 + srow) * K_ + sslot * 8;
  u16* la = ldsA + tid * 8;
  u16* lb = ldsB + tid * 8;

  const int fr = lane & 15;   // fragment row (A: m, B: n)
  const int kg = lane >> 4;   // k-group 0..3

  for (int k0 = 0; k0 < K_; k0 += 64) {
    #pragma unroll
    for (int j = 0; j < 4; j++) gload16(ga + (size_t)(j * 32) * K_ + k0, la + j * 2048);
    #pragma unroll
    for (int j = 0; j < 4; j++) gload16(gb + (size_t)(j * 32) * K_ + k0, lb + j * 2048);
    __syncthreads();   // compiler drains vmcnt before s_barrier

    #pragma unroll
    for (int kk = 0; kk < 2; kk++) {
      const int ps = (((kk << 2) | kg) ^ (fr & 7)) * 8;   // physical slot (swizzled read)
      bf16x8 a[4], b[4];
      #pragma unroll
      for (int mf = 0; mf < 4; mf++)
        a[mf] = *(const bf16x8*)&ldsA[(wm * 64 + mf * 16 + fr) * 64 + ps];
      #pragma unroll
      for (int nf = 0; nf < 4; nf++)
        b[nf] = *(const bf16x8*)&ldsB[(wn * 64 + nf * 16 + fr) * 64 + ps];
      #pragma unroll
      for (int mf = 0; mf < 4; mf++)
        #pragma unroll
        for (int nf = 0; nf < 4; nf++)
          acc[mf][nf] = __builtin_amdgcn_mfma_f32_16x16x32_bf16(a[mf], b[nf], acc[mf][nf], 0, 0, 0);
    }
    __syncthreads();
  }

  float bcol[4];
  #pragma unroll
  for (int nf = 0; nf < 4; nf++) bcol[nf] = bias[n0 + wn * 64 + nf * 16 + fr];
  #pragma unroll
  for (int mf = 0; mf < 4; mf++)
    #pragma unroll
    for (int r = 0; r < 4; r++) {
      const int row = m0 + wm * 64 + mf * 16 + kg * 4 + r;
      #pragma unroll
      for (int nf = 0; nf < 4; nf++) {
        const int col = n0 + wn * 64 + nf * 16 + fr;
        float val = acc[mf][nf][r] + bcol[nf];
        if (BF16OUT) Obf[(size_t)row * H_ + col] = f2bf(val);
        else         Of [(size_t)row * H_ + col] = val;
      }
    }
}

__global__ __launch_bounds__(256) void gemm_qkv(const u16* __restrict__ xb, const u16* __restrict__ wt,
                                                const float* __restrict__ b0, const float* __restrict__ b1,
                                                const float* __restrict__ b2, u16* __restrict__ O) {
  const int z = blockIdx.z;
  const float* bias = z == 0 ? b0 : z == 1 ? b1 : b2;
  gemm_body<1>(xb + (size_t)z * MR_ * K_, wt + (size_t)z * H_ * K_, bias,
               O + (size_t)z * MR_ * H_, nullptr, blockIdx.y, blockIdx.x);
}

__global__ __launch_bounds__(256) void gemm_out(const u16* __restrict__ ctx, const u16* __restrict__ wot,
                                                const float* __restrict__ bo, float* __restrict__ out) {
  gemm_body<0>(ctx, wot, bo, nullptr, out, blockIdx.y, blockIdx.x);
}

// ---------------- flash attention: 4 waves x 16 q-rows, KVBLK=32 ----------------
__global__ __launch_bounds__(256) void attn(const u16* __restrict__ qp, const u16* __restrict__ kp,
                                            const u16* __restrict__ vp, u16* __restrict__ ctx) {
  __shared__ u16 Plds[4][16 * 32];   // per-wave P tile (swizzled)
  __shared__ u16 Vt[64 * 32];        // V^T tile, d-major (swizzled)
  const int bh = blockIdx.y;
  const int b = bh >> 4, h = bh & 15;
  const int q0 = blockIdx.x * 64;
  const int tid = threadIdx.x;
  const int wave = tid >> 6, lane = tid & 63;
  const int fr = lane & 15, kg = lane >> 4;

  const u16* Q  = qp + (size_t)b * S_ * H_ + h * HD_;
  const u16* Kb = kp + (size_t)b * S_ * H_ + h * HD_;
  const u16* Vb = vp + (size_t)b * S_ * H_ + h * HD_;
  u16* O = ctx + (size_t)b * S_ * H_ + h * HD_;

  const int qrow = q0 + wave * 16 + fr;
  bf16x8 qf[2];
  qf[0] = *(const bf16x8*)&Q[(size_t)qrow * H_ + kg * 8];
  qf[1] = *(const bf16x8*)&Q[(size_t)qrow * H_ + 32 + kg * 8];

  f32x4 oacc[4] = {};
  float mrow[4], lrow[4];
  #pragma unroll
  for (int r = 0; r < 4; r++) { mrow[r] = -1e30f; lrow[r] = 0.f; }

  const int vs = tid >> 3;          // s within tile 0..31
  const int vd0 = (tid & 7) * 8;    // d start

  for (int s0 = 0; s0 < S_; s0 += 32) {
    __syncthreads();   // previous iteration's LDS reads complete
    {  // stage V^T (swizzled: slot = s>>3, phys = slot ^ (d&3))
      bf16x8 vv = *(const bf16x8*)&Vb[(size_t)(s0 + vs) * H_ + vd0];
      #pragma unroll
      for (int i = 0; i < 8; i++) {
        int d = vd0 + i;
        int phys = (vs >> 3) ^ (d & 3);
        Vt[d * 32 + phys * 8 + (vs & 7)] = (u16)vv[i];
      }
    }
    // QK^T: A=Q (16 rows), B=K^T (s-cols from global, d-contiguous)
    f32x4 sc[2] = {};
    #pragma unroll
    for (int cf = 0; cf < 2; cf++)
      #pragma unroll
      for (int kk = 0; kk < 2; kk++) {
        bf16x8 kf = *(const bf16x8*)&Kb[(size_t)(s0 + cf * 16 + fr) * H_ + kk * 32 + kg * 8];
        sc[cf] = __builtin_amdgcn_mfma_f32_16x16x32_bf16(qf[kk], kf, sc[cf], 0, 0, 0);
      }
    // online softmax (rows (kg*4+r), 16-lane group reductions)
    const float scale = 0.125f;
    float tmax[4], p0[4], p1[4], psum[4], sf[4];
    #pragma unroll
    for (int r = 0; r < 4; r++) tmax[r] = fmaxf(sc[0][r], sc[1][r]) * scale;
    #pragma unroll
    for (int off = 1; off < 16; off <<= 1)
      #pragma unroll
      for (int r = 0; r < 4; r++) tmax[r] = fmaxf(tmax[r], __shfl_xor(tmax[r], off, 64));
    #pragma unroll
    for (int r = 0; r < 4; r++) {
      float mn = fmaxf(mrow[r], tmax[r]);
      sf[r] = __expf(mrow[r] - mn);
      mrow[r] = mn;
      p0[r] = __expf(sc[0][r] * scale - mn);
      p1[r] = __expf(sc[1][r] * scale - mn);
      psum[r] = p0[r] + p1[r];
    }
    #pragma unroll
    for (int off = 1; off < 16; off <<= 1)
      #pragma unroll
      for (int r = 0; r < 4; r++) psum[r] += __shfl_xor(psum[r], off, 64);
    #pragma unroll
    for (int r = 0; r < 4; r++) {
      lrow[r] = lrow[r] * sf[r] + psum[r];
      #pragma unroll
      for (int nf = 0; nf < 4; nf++) oacc[nf][r] *= sf[r];
    }
    // write P tile (bf16, swizzled)
    u16* Pw = Plds[wave];
    #pragma unroll
    for (int r = 0; r < 4; r++) {
      int prow = kg * 4 + r, sw = prow & 3;
      int c0 = fr, c1 = 16 + fr;
      Pw[prow * 32 + ((c0 >> 3) ^ sw) * 8 + (c0 & 7)] = f2bf(p0[r]);
      Pw[prow * 32 + ((c1 >> 3) ^ sw) * 8 + (c1 & 7)] = f2bf(p1[r]);
    }
    __syncthreads();   // Vt (cross-wave) + P visible
    // PV: A=P (k=s), B=V^T (n=d)
    bf16x8 pf = *(const bf16x8*)&Plds[wave][fr * 32 + (kg ^ (fr & 3)) * 8];
    #pragma unroll
    for (int nf = 0; nf < 4; nf++) {
      int d = nf * 16 + fr;
      bf16x8 vf = *(const bf16x8*)&Vt[d * 32 + (kg ^ (d & 3)) * 8];
      oacc[nf] = __builtin_amdgcn_mfma_f32_16x16x32_bf16(pf, vf, oacc[nf], 0, 0, 0);
    }
  }
  // epilogue: O / l -> ctx (bf16)
  #pragma unroll
  for (int nf = 0; nf < 4; nf++)
    #pragma unroll
    for (int r = 0; r < 4; r++) {
      int row = q0 + wave * 16 + kg * 4 + r;
      O[(size_t)row * H_ + nf * 16 + fr] = f2bf(oacc[nf][r] / lrow[r]);
    }
}

extern "C" void kernel_launch(void* const* d_in, const int* in_sizes, int n_in,
                              void* d_out, int out_size, void* d_ws, size_t ws_size,
                              hipStream_t stream) {
  const float* q  = (const float*)d_in[0];
  const float* k  = (const float*)d_in[1];
  const float* v  = (const float*)d_in[2];
  const float* Wq = (const float*)d_in[3];
  const float* bq = (const float*)d_in[4];
  const float* Wk = (const float*)d_in[5];
  const float* bk = (const float*)d_in[6];
  const float* Wv = (const float*)d_in[7];
  const float* bv = (const float*)d_in[8];
  const float* Wo = (const float*)d_in[9];
  const float* bo = (const float*)d_in[10];
  float* out = (float*)d_out;

  char* ws = (char*)d_ws;
  const size_t MB = 1024 * 1024;
  u16* xb   = (u16*)(ws);             // q,k,v bf16: 3 x 8MB   [0,24)
  u16* wt   = (u16*)(ws + 24 * MB);   // 4 x 2MB transposed W  [24,32)
  u16* qkvp = (u16*)(ws + 32 * MB);   // qp,kp,vp: 3 x 8MB     [32,56)
  u16* ctx  = (u16*)(ws);             // reuse xb region after gemm_qkv

  cvt3  <<<dim3(4096, 1, 3), 256, 0, stream>>>(q, k, v, xb);
  wtrans<<<dim3(32, 32, 4),  256, 0, stream>>>(Wq, Wk, Wv, Wo, wt);
  gemm_qkv<<<dim3(8, 32, 3), 256, 0, stream>>>(xb, wt, bq, bk, bv, qkvp);
  attn  <<<dim3(32, 32),     256, 0, stream>>>(qkvp, qkvp + (size_t)MR_ * H_,
                                               qkvp + (size_t)2 * MR_ * H_, ctx);
  gemm_out<<<dim3(8, 32, 1), 256, 0, stream>>>(ctx, wt + (size_t)3 * H_ * K_, bo, out);
}